// Round 12
// baseline (269.095 us; speedup 1.0000x reference)
//
#include <hip/hip_runtime.h>
#include <hip/hip_bf16.h>

#define N_NODES 100000
#define N_EDGES 1250000
#define IN_DIM  128
#define HID     64
#define OUTD    16
#define ROW     64                 // padded CSR width (in-deg Poisson(12.5), max ~45)
#define NRANGE  8                  // XCD dst-range buckets
#define RSIZE   12500              // N_NODES / NRANGE
#define NCHUNK  256
#define CHUNK   4888               // ceil(N_EDGES/NCHUNK) rounded to x8 (int4-aligned)
#define FILLB   (NRANGE * NCHUNK)  // 2048 fill blocks (8 blocks/CU)
#define MTILE   128
#define GEMMB   ((N_NODES + MTILE - 1) / MTILE)   // 782

typedef __attribute__((ext_vector_type(8))) short  short8;   // 8 bf16 (4 VGPRs)
typedef __attribute__((ext_vector_type(4))) float  floatx4;  // MFMA acc

__device__ __forceinline__ unsigned short f2bf(float f) {   // RNE bf16
    unsigned u = __float_as_uint(f);
    u += 0x7fffu + ((u >> 16) & 1u);
    return (unsigned short)(u >> 16);
}
__device__ __forceinline__ unsigned pk2(float lo, float hi) {  // v_cvt_pk_bf16_f32
    __hip_bfloat162 t = __float22bfloat162_rn(make_float2(lo, hi));
    return *reinterpret_cast<unsigned*>(&t);
}
__device__ __forceinline__ float bf2f_lo(unsigned u) { return __uint_as_float(u << 16); }
__device__ __forceinline__ float bf2f_hi(unsigned u) { return __uint_as_float(u & 0xffff0000u); }

// ---------------- zero cursor + dummy hb row ----------------
__global__ __launch_bounds__(256) void zero_cursor(int* __restrict__ cursor,
                                                   unsigned* __restrict__ hb_dummy) {
    int i = blockIdx.x * 256 + threadIdx.x;
    if (i < N_NODES) cursor[i] = 0;
    if (i < 32) hb_dummy[i] = 0u;          // 128B zero row (pull pad target)
}

// ---------------- XCD-bucketed direct CSR fill (standalone) ----------------
// range r = blockIdx&7: consecutive blocks round-robin XCDs -> each 3.2MB csr
// range + cursor slice served by one XCD's L2, and (standalone) no x-stream
// thrash from gemm blocks. No LDS, 16 VGPR -> full occupancy.
__global__ __launch_bounds__(256) void fill_kernel(const int* __restrict__ src,
                                                   const int* __restrict__ dst,
                                                   int* __restrict__ cursor,
                                                   int* __restrict__ csr) {
    const int r  = blockIdx.x & 7;
    const int c  = blockIdx.x >> 3;
    const int lo = r * RSIZE;
    const int q1 = min(N_EDGES, (c + 1) * CHUNK) >> 2;
    for (int q = (c * CHUNK >> 2) + threadIdx.x; q < q1; q += 256) {
        int4 d4 = ((const int4*)dst)[q];
        int  e  = q << 2;
#pragma unroll
        for (int u = 0; u < 4; u++) {
            int d = (u == 0) ? d4.x : (u == 1) ? d4.y : (u == 2) ? d4.z : d4.w;
            if ((unsigned)(d - lo) < (unsigned)RSIZE) {
                int s = src[e + u];                 // only for kept edges
                int p = atomicAdd(&cursor[d], 1);
                if (p < ROW) csr[(size_t)d * ROW + p] = s;
            }
        }
    }
}

// ---------------- MFMA gemm: h' = (x @ W1) * dis, bf16, MTILE=128 ----------
// Runs AFTER fill -> cursor is the final in-degree -> dis fused at store
// (deletes the scale kernel). A-frags straight from global (packed bf16 cvt);
// only W1^T staged in LDS (16.9KB).
__global__ __launch_bounds__(256) void gemm_mfma(const float* __restrict__ x,
                                                 const float* __restrict__ W1,
                                                 const int* __restrict__ cursor,
                                                 float* __restrict__ dis,
                                                 unsigned short* __restrict__ hb) {
    __shared__ unsigned short w1t[HID][132];   // [n][k] bf16, +132 pitch

    const int m0 = blockIdx.x * MTILE;

    for (int q = threadIdx.x; q < IN_DIM * HID / 4; q += 256) {
        int k = q >> 4, n = (q & 15) * 4;
        float4 wq = ((const float4*)W1)[q];
        w1t[n + 0][k] = f2bf(wq.x);
        w1t[n + 1][k] = f2bf(wq.y);
        w1t[n + 2][k] = f2bf(wq.z);
        w1t[n + 3][k] = f2bf(wq.w);
    }
    __syncthreads();

    const int lane = threadIdx.x & 63;
    const int w    = threadIdx.x >> 6;
    const int mrow = lane & 15;
    const int quad = lane >> 4;
    const int rowa = min(m0 + w * 32 + mrow,      N_NODES - 1);
    const int rowb = min(m0 + w * 32 + 16 + mrow, N_NODES - 1);

    floatx4 acc[2][4] = {};
#pragma unroll
    for (int k0 = 0; k0 < IN_DIM; k0 += 32) {
        union { unsigned u[4]; short8 s; } a0, a1;
        {
            const float4* pa = (const float4*)(x + (size_t)rowa * IN_DIM + k0 + quad * 8);
            float4 u0 = pa[0], v0 = pa[1];
            a0.u[0] = pk2(u0.x, u0.y); a0.u[1] = pk2(u0.z, u0.w);
            a0.u[2] = pk2(v0.x, v0.y); a0.u[3] = pk2(v0.z, v0.w);
            const float4* pb = (const float4*)(x + (size_t)rowb * IN_DIM + k0 + quad * 8);
            float4 u1 = pb[0], v1 = pb[1];
            a1.u[0] = pk2(u1.x, u1.y); a1.u[1] = pk2(u1.z, u1.w);
            a1.u[2] = pk2(v1.x, v1.y); a1.u[3] = pk2(v1.z, v1.w);
        }
        short8 b0 = *(const short8*)&w1t[ 0 + mrow][k0 + quad * 8];
        short8 b1 = *(const short8*)&w1t[16 + mrow][k0 + quad * 8];
        short8 b2 = *(const short8*)&w1t[32 + mrow][k0 + quad * 8];
        short8 b3 = *(const short8*)&w1t[48 + mrow][k0 + quad * 8];
        acc[0][0] = __builtin_amdgcn_mfma_f32_16x16x32_bf16(a0.s, b0, acc[0][0], 0, 0, 0);
        acc[0][1] = __builtin_amdgcn_mfma_f32_16x16x32_bf16(a0.s, b1, acc[0][1], 0, 0, 0);
        acc[0][2] = __builtin_amdgcn_mfma_f32_16x16x32_bf16(a0.s, b2, acc[0][2], 0, 0, 0);
        acc[0][3] = __builtin_amdgcn_mfma_f32_16x16x32_bf16(a0.s, b3, acc[0][3], 0, 0, 0);
        acc[1][0] = __builtin_amdgcn_mfma_f32_16x16x32_bf16(a1.s, b0, acc[1][0], 0, 0, 0);
        acc[1][1] = __builtin_amdgcn_mfma_f32_16x16x32_bf16(a1.s, b1, acc[1][1], 0, 0, 0);
        acc[1][2] = __builtin_amdgcn_mfma_f32_16x16x32_bf16(a1.s, b2, acc[1][2], 0, 0, 0);
        acc[1][3] = __builtin_amdgcn_mfma_f32_16x16x32_bf16(a1.s, b3, acc[1][3], 0, 0, 0);
    }

    // D: row = w*32 + tm*16 + quad*4+reg, col = tn*16 + mrow. dis at store.
#pragma unroll
    for (int tm = 0; tm < 2; tm++) {
#pragma unroll
        for (int reg = 0; reg < 4; reg++) {
            int m = m0 + w * 32 + tm * 16 + quad * 4 + reg;
            if (m < N_NODES) {
                float di = rsqrtf((float)cursor[m] + 1.0f);
#pragma unroll
                for (int tn = 0; tn < 4; tn++)
                    hb[(size_t)m * HID + tn * 16 + mrow] = f2bf(acc[tm][tn][reg] * di);
            }
        }
    }
    if (threadIdx.x < MTILE) {
        int m = m0 + threadIdx.x;
        if (m < N_NODES) dis[m] = rsqrtf((float)cursor[m] + 1.0f);
    }
}

// ------- pull v2: 8 edges in flight x 8 lanes x uint4 (16B) ---------------
// lane = e8*8 + f8. Row preload: lane<cnt -> csr entry; lane==cnt -> i (self
// as virtual edge, hb is pre-scaled so self weight works out); lane>cnt ->
// dummy zero row. Inner loop: bpermute id + one uint4 gather + 8 adds,
// branch-free, 8 gathers in flight per wave.
__global__ __launch_bounds__(256) void pull_epilogue(const unsigned short* __restrict__ hb,
                                                     const int* __restrict__ csr,
                                                     const int* __restrict__ deg,
                                                     const float* __restrict__ dis,
                                                     const float* __restrict__ b1,
                                                     const float* __restrict__ W2,
                                                     const float* __restrict__ b2,
                                                     float* __restrict__ out) {
    const int i    = blockIdx.x * 4 + (threadIdx.x >> 6);
    const int lane = threadIdx.x & 63;
    const int e8   = lane >> 3;    // 0..7 edge slot
    const int f8   = lane & 7;     // feature octet: features f8*8 .. f8*8+7

    const int   cnt = min(deg[i], 63);     // keep one slot for the self edge
    const float di  = dis[i];

    int s_l = N_NODES;                                    // pad -> dummy zero row
    if (lane < cnt) s_l = csr[(size_t)i * ROW + lane];
    if (lane == cnt) s_l = i;                             // self as virtual edge

    float a0 = 0.f, a1 = 0.f, a2 = 0.f, a3 = 0.f,
          a4 = 0.f, a5 = 0.f, a6 = 0.f, a7 = 0.f;
    const int G = (cnt + 1 + 7) >> 3;                     // incl. self
    int g = 0;
    for (; g + 2 <= G; g += 2) {
        int sA = __shfl(s_l, (g << 3) + e8, 64);
        int sB = __shfl(s_l, ((g + 1) << 3) + e8, 64);
        uint4 hA = ((const uint4*)(hb + (size_t)sA * HID))[f8];
        uint4 hB = ((const uint4*)(hb + (size_t)sB * HID))[f8];
        a0 += bf2f_lo(hA.x); a1 += bf2f_hi(hA.x);
        a2 += bf2f_lo(hA.y); a3 += bf2f_hi(hA.y);
        a4 += bf2f_lo(hA.z); a5 += bf2f_hi(hA.z);
        a6 += bf2f_lo(hA.w); a7 += bf2f_hi(hA.w);
        a0 += bf2f_lo(hB.x); a1 += bf2f_hi(hB.x);
        a2 += bf2f_lo(hB.y); a3 += bf2f_hi(hB.y);
        a4 += bf2f_lo(hB.z); a5 += bf2f_hi(hB.z);
        a6 += bf2f_lo(hB.w); a7 += bf2f_hi(hB.w);
    }
    if (g < G) {
        int sA = __shfl(s_l, (g << 3) + e8, 64);
        uint4 hA = ((const uint4*)(hb + (size_t)sA * HID))[f8];
        a0 += bf2f_lo(hA.x); a1 += bf2f_hi(hA.x);
        a2 += bf2f_lo(hA.y); a3 += bf2f_hi(hA.y);
        a4 += bf2f_lo(hA.z); a5 += bf2f_hi(hA.z);
        a6 += bf2f_lo(hA.w); a7 += bf2f_hi(hA.w);
    }

    // combine the 8 edge groups -> every lane holds its full 8-feature sums
#pragma unroll
    for (int d = 8; d < 64; d <<= 1) {
        a0 += __shfl_xor(a0, d, 64); a1 += __shfl_xor(a1, d, 64);
        a2 += __shfl_xor(a2, d, 64); a3 += __shfl_xor(a3, d, 64);
        a4 += __shfl_xor(a4, d, 64); a5 += __shfl_xor(a5, d, 64);
        a6 += __shfl_xor(a6, d, 64); a7 += __shfl_xor(a7, d, 64);
    }

    // final x di, + b1, relu   (features f8*8 .. f8*8+7)
    float4 bA = ((const float4*)b1)[f8 * 2];
    float4 bB = ((const float4*)b1)[f8 * 2 + 1];
    float v0 = fmaxf(fmaf(a0, di, bA.x), 0.f);
    float v1 = fmaxf(fmaf(a1, di, bA.y), 0.f);
    float v2 = fmaxf(fmaf(a2, di, bA.z), 0.f);
    float v3 = fmaxf(fmaf(a3, di, bA.w), 0.f);
    float v4 = fmaxf(fmaf(a4, di, bB.x), 0.f);
    float v5 = fmaxf(fmaf(a5, di, bB.y), 0.f);
    float v6 = fmaxf(fmaf(a6, di, bB.z), 0.f);
    float v7 = fmaxf(fmaf(a7, di, bB.w), 0.f);

    // W2: lane covers hid [f8*8, f8*8+8) x out pair (e8*2, e8*2+1)
    const float2* W2v = (const float2*)W2;           // [HID][OUTD/2] float2 view
    float p0 = 0.f, p1 = 0.f;
    float vv[8] = {v0, v1, v2, v3, v4, v5, v6, v7};
#pragma unroll
    for (int j = 0; j < 8; j++) {
        float2 w = W2v[(f8 * 8 + j) * 8 + e8];       // L1-hot (4KB)
        p0 = fmaf(vv[j], w.x, p0);
        p1 = fmaf(vv[j], w.y, p1);
    }
#pragma unroll
    for (int d = 1; d < 8; d <<= 1) {                // reduce over f8 lanes
        p0 += __shfl_xor(p0, d, 64);
        p1 += __shfl_xor(p1, d, 64);
    }
    float2 b2v = ((const float2*)b2)[e8];
    float lg0 = p0 + b2v.x, lg1 = p1 + b2v.y;

    // log_softmax over 16 logits spread 2-per-e8-group
    float m = fmaxf(lg0, lg1);
#pragma unroll
    for (int d = 8; d < 64; d <<= 1) m = fmaxf(m, __shfl_xor(m, d, 64));
    float s = __expf(lg0 - m) + __expf(lg1 - m);
#pragma unroll
    for (int d = 8; d < 64; d <<= 1) s += __shfl_xor(s, d, 64);
    float lse = __logf(s) + m;

    if (f8 == 0)
        ((float2*)out)[(size_t)i * 8 + e8] = make_float2(lg0 - lse, lg1 - lse);
}

extern "C" void kernel_launch(void* const* d_in, const int* in_sizes, int n_in,
                              void* d_out, int out_size, void* d_ws, size_t ws_size,
                              hipStream_t stream) {
    const float* x   = (const float*)d_in[0];
    const int*   ei  = (const int*)d_in[1];    // int64 in ref -> int32 here
    const float* W1  = (const float*)d_in[2];
    const float* b1  = (const float*)d_in[3];
    const float* W2  = (const float*)d_in[4];
    const float* b2  = (const float*)d_in[5];
    float*       out = (float*)d_out;

    const int* src = ei;             // edge_index[0]
    const int* dst = ei + N_EDGES;   // edge_index[1]

    char* ws = (char*)d_ws;
    size_t off = 0;
    unsigned short* hb = (unsigned short*)(ws + off);
    off += (size_t)(N_NODES + 1) * HID * 2;                                       // 12.8 MB (+pad row)
    int*   csr    = (int*)  (ws + off); off += ((size_t)N_NODES * ROW + ROW) * 4; // 25.6 MB
    int*   cursor = (int*)  (ws + off); off += (size_t)N_NODES * 4;               // 400 KB
    float* dis    = (float*)(ws + off); off += (size_t)N_NODES * 4;               // 400 KB

    zero_cursor<<<(N_NODES + 255) / 256, 256, 0, stream>>>(
        cursor, (unsigned*)(hb + (size_t)N_NODES * HID));
    fill_kernel<<<FILLB, 256, 0, stream>>>(src, dst, cursor, csr);
    gemm_mfma<<<GEMMB, 256, 0, stream>>>(x, W1, cursor, dis, hb);
    pull_epilogue<<<N_NODES / 4, 256, 0, stream>>>(hb, csr, cursor, dis, b1, W2, b2, out);
}

// Round 13
// 232.155 us; speedup vs baseline: 1.1591x; 1.1591x over previous
//
#include <hip/hip_runtime.h>
#include <hip/hip_bf16.h>

#define N_NODES 100000
#define N_EDGES 1250000
#define IN_DIM  128
#define HID     64
#define OUTD    16
#define ROW     64                 // padded CSR width (in-deg Poisson(12.5), max ~45)
#define NRANGE  8                  // XCD dst-range buckets
#define RSIZE   12500              // N_NODES / NRANGE
#define NCHUNK  128
#define CHUNK   9768               // ceil(N_EDGES/NCHUNK) rounded to x8 (int4-aligned)
#define FILLB   (NRANGE * NCHUNK)  // 1024 fill blocks
#define MTILE   128
#define GEMMB   ((N_NODES + MTILE - 1) / MTILE)   // 782

typedef __attribute__((ext_vector_type(8))) short  short8;   // 8 bf16 (4 VGPRs)
typedef __attribute__((ext_vector_type(4))) float  floatx4;  // MFMA acc

__device__ __forceinline__ unsigned short f2bf(float f) {   // RNE bf16
    unsigned u = __float_as_uint(f);
    u += 0x7fffu + ((u >> 16) & 1u);
    return (unsigned short)(u >> 16);
}
__device__ __forceinline__ unsigned pk2(float lo, float hi) {  // v_cvt_pk_bf16_f32
    __hip_bfloat162 t = __float22bfloat162_rn(make_float2(lo, hi));
    return *reinterpret_cast<unsigned*>(&t);
}
__device__ __forceinline__ float bf2f_lo(unsigned u) { return __uint_as_float(u << 16); }
__device__ __forceinline__ float bf2f_hi(unsigned u) { return __uint_as_float(u & 0xffff0000u); }

// ---------------- zero cursor + dummy hb row ----------------
__global__ __launch_bounds__(256) void zero_cursor(int* __restrict__ cursor,
                                                   unsigned* __restrict__ hb_dummy) {
    int i = blockIdx.x * 256 + threadIdx.x;
    if (i < N_NODES) cursor[i] = 0;
    if (i < 32) hb_dummy[i] = 0u;          // 128B zero row (pull pad target)
}

// ------- fused: XCD-bucketed direct CSR fill + MFMA h = x@W1 (bf16, raw) ---
// MEASURED 83us in R11 -- kept byte-identical.
// fill blocks [0,FILLB): range r = blockIdx&7 (consecutive blocks round-robin
// XCDs -> each 3.2MB csr range + cursor slice served by one XCD's L2).
// gemm blocks: MTILE=128 rows; A-frags read DIRECTLY from global (packed
// bf16 cvt) -> only W1^T staged in LDS (16.9KB). The latency-bound fill
// overlaps the compute-bound gemm in one dispatch (de-fusing costs ~65us,
// measured R12). h stored UNSCALED: no degree dependency.
__global__ __launch_bounds__(256) void fill_gemm(const float* __restrict__ x,
                                                 const float* __restrict__ W1,
                                                 const int* __restrict__ src,
                                                 const int* __restrict__ dst,
                                                 int* __restrict__ cursor,
                                                 int* __restrict__ csr,
                                                 unsigned short* __restrict__ hb) {
    __shared__ unsigned short w1t[HID][132];   // [n][k] bf16, +132 pitch

    if (blockIdx.x < FILLB) {
        const int r  = blockIdx.x & 7;
        const int c  = blockIdx.x >> 3;
        const int lo = r * RSIZE;
        const int q1 = min(N_EDGES, (c + 1) * CHUNK) >> 2;
        for (int q = (c * CHUNK >> 2) + threadIdx.x; q < q1; q += 256) {
            int4 d4 = ((const int4*)dst)[q];
            int  e  = q << 2;
#pragma unroll
            for (int u = 0; u < 4; u++) {
                int d = (u == 0) ? d4.x : (u == 1) ? d4.y : (u == 2) ? d4.z : d4.w;
                if ((unsigned)(d - lo) < (unsigned)RSIZE) {
                    int s = src[e + u];                 // only for kept edges
                    int p = atomicAdd(&cursor[d], 1);
                    if (p < ROW) csr[(size_t)d * ROW + p] = s;
                }
            }
        }
        return;
    }

    // ---- gemm part ----
    const int m0 = (blockIdx.x - FILLB) * MTILE;

    for (int q = threadIdx.x; q < IN_DIM * HID / 4; q += 256) {
        int k = q >> 4, n = (q & 15) * 4;
        float4 wq = ((const float4*)W1)[q];
        w1t[n + 0][k] = f2bf(wq.x);
        w1t[n + 1][k] = f2bf(wq.y);
        w1t[n + 2][k] = f2bf(wq.z);
        w1t[n + 3][k] = f2bf(wq.w);
    }
    __syncthreads();

    const int lane = threadIdx.x & 63;
    const int w    = threadIdx.x >> 6;
    const int mrow = lane & 15;
    const int quad = lane >> 4;
    const int rowa = min(m0 + w * 32 + mrow,      N_NODES - 1);
    const int rowb = min(m0 + w * 32 + 16 + mrow, N_NODES - 1);

    floatx4 acc[2][4] = {};
#pragma unroll
    for (int k0 = 0; k0 < IN_DIM; k0 += 32) {
        union { unsigned u[4]; short8 s; } a0, a1;
        {
            const float4* pa = (const float4*)(x + (size_t)rowa * IN_DIM + k0 + quad * 8);
            float4 u0 = pa[0], v0 = pa[1];
            a0.u[0] = pk2(u0.x, u0.y); a0.u[1] = pk2(u0.z, u0.w);
            a0.u[2] = pk2(v0.x, v0.y); a0.u[3] = pk2(v0.z, v0.w);
            const float4* pb = (const float4*)(x + (size_t)rowb * IN_DIM + k0 + quad * 8);
            float4 u1 = pb[0], v1 = pb[1];
            a1.u[0] = pk2(u1.x, u1.y); a1.u[1] = pk2(u1.z, u1.w);
            a1.u[2] = pk2(v1.x, v1.y); a1.u[3] = pk2(v1.z, v1.w);
        }
        short8 b0 = *(const short8*)&w1t[ 0 + mrow][k0 + quad * 8];
        short8 b1 = *(const short8*)&w1t[16 + mrow][k0 + quad * 8];
        short8 b2 = *(const short8*)&w1t[32 + mrow][k0 + quad * 8];
        short8 b3 = *(const short8*)&w1t[48 + mrow][k0 + quad * 8];
        acc[0][0] = __builtin_amdgcn_mfma_f32_16x16x32_bf16(a0.s, b0, acc[0][0], 0, 0, 0);
        acc[0][1] = __builtin_amdgcn_mfma_f32_16x16x32_bf16(a0.s, b1, acc[0][1], 0, 0, 0);
        acc[0][2] = __builtin_amdgcn_mfma_f32_16x16x32_bf16(a0.s, b2, acc[0][2], 0, 0, 0);
        acc[0][3] = __builtin_amdgcn_mfma_f32_16x16x32_bf16(a0.s, b3, acc[0][3], 0, 0, 0);
        acc[1][0] = __builtin_amdgcn_mfma_f32_16x16x32_bf16(a1.s, b0, acc[1][0], 0, 0, 0);
        acc[1][1] = __builtin_amdgcn_mfma_f32_16x16x32_bf16(a1.s, b1, acc[1][1], 0, 0, 0);
        acc[1][2] = __builtin_amdgcn_mfma_f32_16x16x32_bf16(a1.s, b2, acc[1][2], 0, 0, 0);
        acc[1][3] = __builtin_amdgcn_mfma_f32_16x16x32_bf16(a1.s, b3, acc[1][3], 0, 0, 0);
    }

    // D: row = w*32 + tm*16 + quad*4+reg, col = tn*16 + mrow (unscaled store)
#pragma unroll
    for (int tm = 0; tm < 2; tm++) {
#pragma unroll
        for (int reg = 0; reg < 4; reg++) {
            int m = m0 + w * 32 + tm * 16 + quad * 4 + reg;
            if (m < N_NODES) {
#pragma unroll
                for (int tn = 0; tn < 4; tn++)
                    hb[(size_t)m * HID + tn * 16 + mrow] = f2bf(acc[tm][tn][reg]);
            }
        }
    }
}

// ------- pull: weighted sum + bias/relu + W2 + log_softmax -----------------
// R9's measured-optimal 4-edge x 16-lane x uint2 layout. hb is UNSCALED, so
// each lane preloads w_l = rsqrt(deg[s_l]+1) ONCE in the preamble (4B
// L2-resident gather) and the inner loop uses fmaf with shuffled weights.
// agg_i = di * (sum_s w_s*h_s + di*h_i). Deletes the scale kernel entirely.
__global__ __launch_bounds__(256) void pull_epilogue(const unsigned short* __restrict__ hb,
                                                     const int* __restrict__ csr,
                                                     const int* __restrict__ deg,
                                                     const float* __restrict__ b1,
                                                     const float* __restrict__ W2,
                                                     const float* __restrict__ b2,
                                                     float* __restrict__ out) {
    const int i     = blockIdx.x * 4 + (threadIdx.x >> 6);
    const int lane  = threadIdx.x & 63;
    const int e_sub = lane >> 4;   // 0..3
    const int f4    = lane & 15;   // bf16x4 slot of HID

    const int   cnt = min(deg[i], ROW);
    const float di  = rsqrtf((float)deg[i] + 1.0f);

    int   s_l = N_NODES;                                  // pad -> dummy zero row
    float w_l = 0.f;
    if (lane < cnt) {
        s_l = csr[(size_t)i * ROW + lane];
        w_l = rsqrtf((float)deg[s_l] + 1.0f);             // L2-resident 4B gather
    }

    uint2 hs = ((const uint2*)(hb + (size_t)i * HID))[f4];  // self slice (raw h_i)

    float ax = 0.f, ay = 0.f, az = 0.f, aw = 0.f;
    const int G = (cnt + 3) >> 2;
    int g = 0;
    for (; g + 2 <= G; g += 2) {
        int e0 = (g << 2) + e_sub, e1 = e0 + 4;
        int   s0 = __shfl(s_l, e0, 64), s1 = __shfl(s_l, e1, 64);
        float w0 = __shfl(w_l, e0, 64), w1 = __shfl(w_l, e1, 64);
        uint2 a = ((const uint2*)(hb + (size_t)s0 * HID))[f4];
        uint2 b = ((const uint2*)(hb + (size_t)s1 * HID))[f4];
        ax = fmaf(bf2f_lo(a.x), w0, ax); ay = fmaf(bf2f_hi(a.x), w0, ay);
        az = fmaf(bf2f_lo(a.y), w0, az); aw = fmaf(bf2f_hi(a.y), w0, aw);
        ax = fmaf(bf2f_lo(b.x), w1, ax); ay = fmaf(bf2f_hi(b.x), w1, ay);
        az = fmaf(bf2f_lo(b.y), w1, az); aw = fmaf(bf2f_hi(b.y), w1, aw);
    }
    if (g < G) {
        int e0 = (g << 2) + e_sub;
        int   s0 = __shfl(s_l, e0, 64);
        float w0 = __shfl(w_l, e0, 64);
        uint2 a = ((const uint2*)(hb + (size_t)s0 * HID))[f4];
        ax = fmaf(bf2f_lo(a.x), w0, ax); ay = fmaf(bf2f_hi(a.x), w0, ay);
        az = fmaf(bf2f_lo(a.y), w0, az); aw = fmaf(bf2f_hi(a.y), w0, aw);
    }

    // combine the 4 edge groups -> every lane holds the full slice sum
    ax += __shfl_xor(ax, 16, 64); ax += __shfl_xor(ax, 32, 64);
    ay += __shfl_xor(ay, 16, 64); ay += __shfl_xor(ay, 32, 64);
    az += __shfl_xor(az, 16, 64); az += __shfl_xor(az, 32, 64);
    aw += __shfl_xor(aw, 16, 64); aw += __shfl_xor(aw, 32, 64);

    // + self (weight di), x di, + b1, relu
    float4 b1v = ((const float4*)b1)[f4];
    float t0 = fmaf(bf2f_lo(hs.x), di, ax);
    float t1 = fmaf(bf2f_hi(hs.x), di, ay);
    float t2 = fmaf(bf2f_lo(hs.y), di, az);
    float t3 = fmaf(bf2f_hi(hs.y), di, aw);
    float v0 = fmaxf(fmaf(t0, di, b1v.x), 0.f);
    float v1 = fmaxf(fmaf(t1, di, b1v.y), 0.f);
    float v2 = fmaxf(fmaf(t2, di, b1v.z), 0.f);
    float v3 = fmaxf(fmaf(t3, di, b1v.w), 0.f);

    // W2: lane covers hid slice [4*f4,4*f4+4) x out slice [4*e_sub,4*e_sub+4)
    const float4* W2v = (const float4*)W2;         // [HID][OUTD/4] float4 view
    float4 w0 = W2v[(4 * f4 + 0) * 4 + e_sub];
    float4 w1 = W2v[(4 * f4 + 1) * 4 + e_sub];
    float4 w2 = W2v[(4 * f4 + 2) * 4 + e_sub];
    float4 w3 = W2v[(4 * f4 + 3) * 4 + e_sub];
    float p0 = v0 * w0.x + v1 * w1.x + v2 * w2.x + v3 * w3.x;
    float p1 = v0 * w0.y + v1 * w1.y + v2 * w2.y + v3 * w3.y;
    float p2 = v0 * w0.z + v1 * w1.z + v2 * w2.z + v3 * w3.z;
    float p3 = v0 * w0.w + v1 * w1.w + v2 * w2.w + v3 * w3.w;
#pragma unroll
    for (int d = 1; d < 16; d <<= 1) {
        p0 += __shfl_xor(p0, d, 64);
        p1 += __shfl_xor(p1, d, 64);
        p2 += __shfl_xor(p2, d, 64);
        p3 += __shfl_xor(p3, d, 64);
    }
    float4 b2v = ((const float4*)b2)[e_sub];
    float lg0 = p0 + b2v.x, lg1 = p1 + b2v.y, lg2 = p2 + b2v.z, lg3 = p3 + b2v.w;

    // log_softmax over 16 logits spread across e_sub groups
    float m = fmaxf(fmaxf(lg0, lg1), fmaxf(lg2, lg3));
    m = fmaxf(m, __shfl_xor(m, 16, 64));
    m = fmaxf(m, __shfl_xor(m, 32, 64));
    float s = __expf(lg0 - m) + __expf(lg1 - m) + __expf(lg2 - m) + __expf(lg3 - m);
    s += __shfl_xor(s, 16, 64);
    s += __shfl_xor(s, 32, 64);
    float lse = __logf(s) + m;

    if (f4 == 0) {
        float4 o = make_float4(lg0 - lse, lg1 - lse, lg2 - lse, lg3 - lse);
        ((float4*)out)[(size_t)i * 4 + e_sub] = o;
    }
}

extern "C" void kernel_launch(void* const* d_in, const int* in_sizes, int n_in,
                              void* d_out, int out_size, void* d_ws, size_t ws_size,
                              hipStream_t stream) {
    const float* x   = (const float*)d_in[0];
    const int*   ei  = (const int*)d_in[1];    // int64 in ref -> int32 here
    const float* W1  = (const float*)d_in[2];
    const float* b1  = (const float*)d_in[3];
    const float* W2  = (const float*)d_in[4];
    const float* b2  = (const float*)d_in[5];
    float*       out = (float*)d_out;

    const int* src = ei;             // edge_index[0]
    const int* dst = ei + N_EDGES;   // edge_index[1]

    char* ws = (char*)d_ws;
    size_t off = 0;
    unsigned short* hb = (unsigned short*)(ws + off);
    off += (size_t)(N_NODES + 1) * HID * 2;                                       // 12.8 MB (+pad row)
    int*   csr    = (int*)  (ws + off); off += ((size_t)N_NODES * ROW + ROW) * 4; // 25.6 MB
    int*   cursor = (int*)  (ws + off); off += (size_t)N_NODES * 4;               // 400 KB

    zero_cursor<<<(N_NODES + 255) / 256, 256, 0, stream>>>(
        cursor, (unsigned*)(hb + (size_t)N_NODES * HID));
    fill_gemm<<<FILLB + GEMMB, 256, 0, stream>>>(x, W1, src, dst, cursor, csr, hb);
    pull_epilogue<<<N_NODES / 4, 256, 0, stream>>>(hb, csr, cursor, b1, W2, b2, out);
}